// Round 1
// baseline (4978.951 us; speedup 1.0000x reference)
//
#include <hip/hip_runtime.h>
#include <math.h>

#define BSZ 64
#define TLEN 256
#define LSND 65536
#define ZSTR 132          // 129 padded to 132 (16B-aligned rows, zero pads)
#define LSTM_G 128        // persistent LSTM blocks (8 b-tiles x 16 j-tiles)

__device__ __forceinline__ float sigm(float x) { return 1.f / (1.f + __expf(-x)); }
__device__ __forceinline__ float tanh_f(float x) {
  float e = __expf(-2.f * fabsf(x));
  float t = (1.f - e) / (1.f + e);
  return copysignf(t, x);
}

// K1: fold linear into w_ih:  Wc[n][j] = sum_k w_ih[n,k]*lin_w[k,j]  (1024 x 132, pads zero)
//     bc[n] = w_ih[n,:]@lin_b + b_ih[n] + b_hh[n]
__global__ __launch_bounds__(256) void prep_kernel(
    const float* __restrict__ w_ih, const float* __restrict__ lin_w,
    const float* __restrict__ lin_b, const float* __restrict__ b_ih,
    const float* __restrict__ b_hh, float* __restrict__ Wc, float* __restrict__ bc)
{
  __shared__ float sRow[256];
  const int n = blockIdx.x;
  const int j = threadIdx.x;
  sRow[j] = w_ih[n * 256 + j];
  __syncthreads();
  if (j < ZSTR) {
    float acc = 0.f;
    if (j < 129) {
      for (int k = 0; k < 256; ++k) acc += sRow[k] * lin_w[k * 129 + j];
    }
    Wc[n * ZSTR + j] = acc;
  } else if (j == 255) {
    float acc = b_ih[n] + b_hh[n];
    for (int k = 0; k < 256; ++k) acc += sRow[k] * lin_b[k];
    bc[n] = acc;
  }
}

// K1b: w3t[s][o] = conv3_w[o][s], s = c*3+k in [0,96), o in [0,128)
__global__ __launch_bounds__(256) void transpose_w3(const float* __restrict__ w3,
                                                    float* __restrict__ w3t)
{
  int i = blockIdx.x * 256 + threadIdx.x;
  if (i < 96 * 128) { int s = i >> 7, o = i & 127; w3t[i] = w3[o * 96 + s]; }
}

// K2: per (t,b): gather window -> conv1 (3 dots of 2046) -> conv2(32ch,k3,pad1,relu)
//     -> conv3(128ch,k3) -> z[t][b][0..128] = {interval, y3}, pads zeroed.
__global__ __launch_bounds__(64) void conv_kernel(
    const int* __restrict__ alpha, const float* __restrict__ sound,
    const float* __restrict__ w1, const float* __restrict__ b1v,
    const float* __restrict__ w2, const float* __restrict__ b2,
    const float* __restrict__ w3t, const float* __restrict__ b3,
    float* __restrict__ z)
{
  __shared__ float win[2048];
  __shared__ float sY2[96];
  const int l = threadIdx.x;
  const int b = blockIdx.x >> 8;     // consecutive blocks = consecutive t (window overlap locality)
  const int t = blockIdx.x & 255;
  const int a = alpha[b * TLEN + t];
  const int a0 = a - 1024;
  const float* srow = sound + (size_t)b * LSND;
  for (int x = l; x < 2048; x += 64) {
    int p = a0 + x;
    win[x] = (p >= 0 && p < LSND) ? srow[p] : 0.f;
  }
  __syncthreads();
  float acc0 = 0.f, acc1 = 0.f, acc2 = 0.f;
  for (int f = l; f < 2046; f += 64) {
    float wv = w1[f];
    acc0 += win[f] * wv;
    acc1 += win[f + 1] * wv;
    acc2 += win[f + 2] * wv;
  }
  for (int m = 32; m; m >>= 1) {
    acc0 += __shfl_xor(acc0, m);
    acc1 += __shfl_xor(acc1, m);
    acc2 += __shfl_xor(acc2, m);
  }
  const float bb = b1v[0];
  const float y11 = acc0 + bb, y12 = acc1 + bb, y13 = acc2 + bb;
  // y2[c][lp] = relu(sum_k y1p[lp+k]*w2[c,k] + b2[c]), y1p = {0,y11,y12,y13,0}
  {
    int s = l;
    int c = s / 3, lp = s - c * 3;
    float wA = w2[c * 3], wB = w2[c * 3 + 1], wC = w2[c * 3 + 2];
    float v = (lp == 0) ? (y11 * wB + y12 * wC)
            : (lp == 1) ? (y11 * wA + y12 * wB + y13 * wC)
                        : (y12 * wA + y13 * wB);
    sY2[s] = fmaxf(v + b2[c], 0.f);
    if (l < 32) {
      s = 64 + l; c = s / 3; lp = s - c * 3;
      wA = w2[c * 3]; wB = w2[c * 3 + 1]; wC = w2[c * 3 + 2];
      v = (lp == 0) ? (y11 * wB + y12 * wC)
        : (lp == 1) ? (y11 * wA + y12 * wB + y13 * wC)
                    : (y12 * wA + y13 * wB);
      sY2[s] = fmaxf(v + b2[c], 0.f);
    }
  }
  __syncthreads();
  float o0 = b3[l], o1 = b3[l + 64];
  for (int s = 0; s < 96; ++s) {
    float yv = sY2[s];
    o0 += yv * w3t[s * 128 + l];
    o1 += yv * w3t[s * 128 + l + 64];
  }
  float* zrow = z + ((size_t)t * BSZ + b) * ZSTR;
  zrow[1 + l] = o0;
  zrow[1 + l + 64] = o1;
  if (l == 0) {
    int prev = (t > 0) ? alpha[b * TLEN + t - 1] : 0;
    zrow[0] = (float)(a - prev);
  }
  if (l < 3) zrow[129 + l] = 0.f;
}

// K3: persistent LSTM. 128 blocks x 256 threads, 1 block/CU (LDS ~113KB).
// Block (btile,jtile) owns b rows [btile*8, +8) and hidden cols [jtile*16, +16) (all 4 gates).
// Per step: stage h slice -> 2 dots/thread (K=256) -> gate exchange via LDS -> c,h update
// -> release (fence + atomic) -> prefetch z/xw for t+1 (hides barrier latency) -> acquire wait.
__global__ void __launch_bounds__(256, 1) lstm_kernel(
    const float* __restrict__ z, const float* __restrict__ Wc,
    const float* __restrict__ bc, const float* __restrict__ w_hh,
    float* __restrict__ hbuf, int* __restrict__ bar)
{
  __shared__ float sW[64][260];    // w_hh rows (gate*16+jl), padded stride (bank spread)
  __shared__ float sWC[64][132];   // folded input-weight rows
  __shared__ float sH[8][260];     // h slice for this step
  __shared__ float sZ[8][132];     // z rows for next step
  __shared__ float sG[512];        // gate pre-activations exchange
  __shared__ float sBC[64];

  const int tid = threadIdx.x;
  const int btile = (int)blockIdx.x >> 4;   // 0..7
  const int jtile = (int)blockIdx.x & 15;   // 0..15
  const int nl = tid >> 3;                  // 0..31 (row for acc0; +32 for acc1)
  const int bl = tid & 7;                   // local b

  for (int i = tid; i < 64 * 64; i += 256) {          // 64 rows x 64 float4
    int r = i >> 6, c4 = (i & 63) << 2;
    int ng = ((r >> 4) << 8) + (jtile << 4) + (r & 15);
    *(float4*)&sW[r][c4] = *(const float4*)&w_hh[ng * 256 + c4];
  }
  for (int i = tid; i < 64 * 33; i += 256) {          // 64 rows x 33 float4
    int r = i / 33, c4 = (i - r * 33) << 2;
    int ng = ((r >> 4) << 8) + (jtile << 4) + (r & 15);
    *(float4*)&sWC[r][c4] = *(const float4*)&Wc[ng * ZSTR + c4];
  }
  if (tid < 64) {
    int ng = ((tid >> 4) << 8) + (jtile << 4) + (tid & 15);
    sBC[tid] = bc[ng];
  }
  __syncthreads();

  // stage z(t=0) and compute xw for t=0
  for (int i = tid; i < 8 * 33; i += 256) {
    int r = i / 33, c4 = (i - r * 33) << 2;
    *(float4*)&sZ[r][c4] = *(const float4*)&z[(size_t)((btile << 3) + r) * ZSTR + c4];
  }
  __syncthreads();
  float xw0 = sBC[nl], xw1 = sBC[nl + 32];
  #pragma unroll
  for (int k = 0; k < ZSTR; k += 4) {
    float4 zv = *(const float4*)&sZ[bl][k];
    float4 wa = *(const float4*)&sWC[nl][k];
    float4 wb = *(const float4*)&sWC[nl + 32][k];
    xw0 += zv.x * wa.x + zv.y * wa.y + zv.z * wa.z + zv.w * wa.w;
    xw1 += zv.x * wb.x + zv.y * wb.y + zv.z * wb.z + zv.w * wb.w;
  }

  float c_reg = 0.f;
  for (int t = 0; t < TLEN; ++t) {
    if (t > 0) {
      if (tid == 0) {
        const int target = t * LSTM_G;
        while (__hip_atomic_load(bar, __ATOMIC_RELAXED, __HIP_MEMORY_SCOPE_AGENT) < target)
          __builtin_amdgcn_s_sleep(1);
        __threadfence();   // acquire: invalidate L1/L2 so h reads are fresh
      }
      __syncthreads();
    }
    const float* __restrict__ hsrc = hbuf + ((t & 1) << 14);
    for (int i = tid; i < 512; i += 256) {            // 8 rows x 64 float4
      int r = i >> 6, c4 = (i & 63) << 2;
      *(float4*)&sH[r][c4] = *(const float4*)&hsrc[(((btile << 3) + r) << 8) + c4];
    }
    __syncthreads();

    float a0 = xw0, a1 = xw1;
    #pragma unroll 8
    for (int k = 0; k < 256; k += 4) {
      float4 hv = *(const float4*)&sH[bl][k];
      float4 wa = *(const float4*)&sW[nl][k];
      float4 wb = *(const float4*)&sW[nl + 32][k];
      a0 += hv.x * wa.x + hv.y * wa.y + hv.z * wa.z + hv.w * wa.w;
      a1 += hv.x * wb.x + hv.y * wb.y + hv.z * wb.z + hv.w * wb.w;
    }
    sG[(nl << 3) + bl] = a0;
    sG[((nl + 32) << 3) + bl] = a1;
    __syncthreads();

    if (tid < 128) {
      const int jl = tid >> 3, bb = tid & 7;
      float gi = sG[(jl << 3) + bb];             // gate i : rows 0..15
      float gf = sG[((16 + jl) << 3) + bb];      // gate f : rows 16..31
      float gg = sG[((32 + jl) << 3) + bb];      // gate g : rows 32..47
      float go = sG[((48 + jl) << 3) + bb];      // gate o : rows 48..63
      c_reg = sigm(gf) * c_reg + sigm(gi) * tanh_f(gg);
      float hv = sigm(go) * tanh_f(c_reg);
      float* hdst = hbuf + (((t + 1) & 1) << 14);
      hdst[(((btile << 3) + bb) << 8) + (jtile << 4) + jl] = hv;
    }
    __threadfence();          // release: drain h stores to coherence point
    __syncthreads();
    if (tid == 0)
      __hip_atomic_fetch_add(bar, 1, __ATOMIC_RELEASE, __HIP_MEMORY_SCOPE_AGENT);

    if (t + 1 < TLEN) {
      // prefetch z(t+1) + xw(t+1): independent of h, overlaps barrier latency
      for (int i = tid; i < 8 * 33; i += 256) {
        int r = i / 33, c4 = (i - r * 33) << 2;
        *(float4*)&sZ[r][c4] =
            *(const float4*)&z[((size_t)(t + 1) * BSZ + (btile << 3) + r) * ZSTR + c4];
      }
      __syncthreads();
      xw0 = sBC[nl]; xw1 = sBC[nl + 32];
      #pragma unroll
      for (int k = 0; k < ZSTR; k += 4) {
        float4 zv = *(const float4*)&sZ[bl][k];
        float4 wa = *(const float4*)&sWC[nl][k];
        float4 wb = *(const float4*)&sWC[nl + 32][k];
        xw0 += zv.x * wa.x + zv.y * wa.y + zv.z * wa.z + zv.w * wa.w;
        xw1 += zv.x * wb.x + zv.y * wb.y + zv.z * wb.z + zv.w * wb.w;
      }
    }
  }
}

// K4: head: out[b] = sigmoid(relu(h@out1_w.T + out1_b) @ out2_w.T + out2_b)
__global__ __launch_bounds__(256) void head_kernel(
    const float* __restrict__ hbuf, const float* __restrict__ o1w,
    const float* __restrict__ o1b, const float* __restrict__ o2w,
    const float* __restrict__ o2b, float* __restrict__ out)
{
  __shared__ float sR[32];
  const int b = blockIdx.x;
  const int tid = threadIdx.x;
  const int m = tid >> 3, g = tid & 7;
  const float* h = hbuf + b * 256;      // final h lives in hbuf[0]
  float acc = 0.f;
  for (int k = g * 32; k < g * 32 + 32; ++k) acc += h[k] * o1w[m * 256 + k];
  acc += __shfl_xor(acc, 1); acc += __shfl_xor(acc, 2); acc += __shfl_xor(acc, 4);
  if (g == 0) sR[m] = fmaxf(acc + o1b[m], 0.f);
  __syncthreads();
  if (tid == 0) {
    float s = o2b[0];
    for (int mm = 0; mm < 32; ++mm) s += sR[mm] * o2w[mm];
    out[b] = sigm(s);
  }
}

extern "C" void kernel_launch(void* const* d_in, const int* in_sizes, int n_in,
                              void* d_out, int out_size, void* d_ws, size_t ws_size,
                              hipStream_t stream) {
  (void)in_sizes; (void)n_in; (void)out_size; (void)ws_size;
  const int*   alpha = (const int*)  d_in[0];
  const float* sound = (const float*)d_in[1];
  const float* w1    = (const float*)d_in[2];
  const float* b1    = (const float*)d_in[3];
  const float* w2    = (const float*)d_in[4];
  const float* b2    = (const float*)d_in[5];
  const float* w3    = (const float*)d_in[6];
  const float* b3    = (const float*)d_in[7];
  const float* linw  = (const float*)d_in[8];
  const float* linb  = (const float*)d_in[9];
  const float* wih   = (const float*)d_in[10];
  const float* whh   = (const float*)d_in[11];
  const float* bih   = (const float*)d_in[12];
  const float* bhh   = (const float*)d_in[13];
  const float* o1w   = (const float*)d_in[14];
  const float* o1b   = (const float*)d_in[15];
  const float* o2w   = (const float*)d_in[16];
  const float* o2b   = (const float*)d_in[17];

  float* z    = (float*)d_ws;            // T*B*132           = 2,162,688 f
  float* Wc   = z + 2162688;             // 1024*132          =   135,168 f
  float* bc   = Wc + 135168;             // 1024 f
  float* w3t  = bc + 1024;               // 96*128            =    12,288 f
  float* hbuf = w3t + 12288;             // 2*64*256          =    32,768 f
  int*   bar  = (int*)(hbuf + 32768);    // counter

  hipMemsetAsync(hbuf, 0, 32768 * 4 + 256, stream);   // h0 = 0, barrier = 0

  prep_kernel<<<1024, 256, 0, stream>>>(wih, linw, linb, bih, bhh, Wc, bc);
  transpose_w3<<<48, 256, 0, stream>>>(w3, w3t);
  conv_kernel<<<BSZ * TLEN, 64, 0, stream>>>(alpha, sound, w1, b1, w2, b2, w3t, b3, z);
  lstm_kernel<<<LSTM_G, 256, 0, stream>>>(z, Wc, bc, whh, hbuf, bar);
  head_kernel<<<BSZ, 256, 0, stream>>>(hbuf, o1w, o1b, o2w, o2b, (float*)d_out);
}

// Round 2
// 2096.662 us; speedup vs baseline: 2.3747x; 2.3747x over previous
//
#include <hip/hip_runtime.h>
#include <math.h>

#define BSZ 64
#define TLEN 256
#define LSND 65536
#define ZSTR 132          // 129 padded to 132 (16B-aligned rows, zero pads)
#define LSTM_G 128        // persistent LSTM blocks (8 b-tiles x 16 j-tiles)

__device__ __forceinline__ float sigm(float x) { return 1.f / (1.f + __expf(-x)); }
__device__ __forceinline__ float tanh_f(float x) {
  float e = __expf(-2.f * fabsf(x));
  float t = (1.f - e) / (1.f + e);
  return copysignf(t, x);
}

// K1: fold linear into w_ih:  Wc[n][j] = sum_k w_ih[n,k]*lin_w[k,j]  (1024 x 132, pads zero)
//     bc[n] = w_ih[n,:]@lin_b + b_ih[n] + b_hh[n]
__global__ __launch_bounds__(256) void prep_kernel(
    const float* __restrict__ w_ih, const float* __restrict__ lin_w,
    const float* __restrict__ lin_b, const float* __restrict__ b_ih,
    const float* __restrict__ b_hh, float* __restrict__ Wc, float* __restrict__ bc)
{
  __shared__ float sRow[256];
  const int n = blockIdx.x;
  const int j = threadIdx.x;
  sRow[j] = w_ih[n * 256 + j];
  __syncthreads();
  if (j < ZSTR) {
    float acc = 0.f;
    if (j < 129) {
      for (int k = 0; k < 256; ++k) acc += sRow[k] * lin_w[k * 129 + j];
    }
    Wc[n * ZSTR + j] = acc;
  } else if (j == 255) {
    float acc = b_ih[n] + b_hh[n];
    for (int k = 0; k < 256; ++k) acc += sRow[k] * lin_b[k];
    bc[n] = acc;
  }
}

// K1b: w3t[s][o] = conv3_w[o][s], s = c*3+k in [0,96), o in [0,128)
__global__ __launch_bounds__(256) void transpose_w3(const float* __restrict__ w3,
                                                    float* __restrict__ w3t)
{
  int i = blockIdx.x * 256 + threadIdx.x;
  if (i < 96 * 128) { int s = i >> 7, o = i & 127; w3t[i] = w3[o * 96 + s]; }
}

// K2: per (t,b): gather window -> conv1 (3 dots of 2046) -> conv2(32ch,k3,pad1,relu)
//     -> conv3(128ch,k3) -> z[t][b][0..128] = {interval, y3}, pads zeroed.
__global__ __launch_bounds__(64) void conv_kernel(
    const int* __restrict__ alpha, const float* __restrict__ sound,
    const float* __restrict__ w1, const float* __restrict__ b1v,
    const float* __restrict__ w2, const float* __restrict__ b2,
    const float* __restrict__ w3t, const float* __restrict__ b3,
    float* __restrict__ z)
{
  __shared__ float win[2048];
  __shared__ float sY2[96];
  const int l = threadIdx.x;
  const int b = blockIdx.x >> 8;
  const int t = blockIdx.x & 255;
  const int a = alpha[b * TLEN + t];
  const int a0 = a - 1024;
  const float* srow = sound + (size_t)b * LSND;
  for (int x = l; x < 2048; x += 64) {
    int p = a0 + x;
    win[x] = (p >= 0 && p < LSND) ? srow[p] : 0.f;
  }
  __syncthreads();
  float acc0 = 0.f, acc1 = 0.f, acc2 = 0.f;
  for (int f = l; f < 2046; f += 64) {
    float wv = w1[f];
    acc0 += win[f] * wv;
    acc1 += win[f + 1] * wv;
    acc2 += win[f + 2] * wv;
  }
  for (int m = 32; m; m >>= 1) {
    acc0 += __shfl_xor(acc0, m);
    acc1 += __shfl_xor(acc1, m);
    acc2 += __shfl_xor(acc2, m);
  }
  const float bb = b1v[0];
  const float y11 = acc0 + bb, y12 = acc1 + bb, y13 = acc2 + bb;
  {
    int s = l;
    int c = s / 3, lp = s - c * 3;
    float wA = w2[c * 3], wB = w2[c * 3 + 1], wC = w2[c * 3 + 2];
    float v = (lp == 0) ? (y11 * wB + y12 * wC)
            : (lp == 1) ? (y11 * wA + y12 * wB + y13 * wC)
                        : (y12 * wA + y13 * wB);
    sY2[s] = fmaxf(v + b2[c], 0.f);
    if (l < 32) {
      s = 64 + l; c = s / 3; lp = s - c * 3;
      wA = w2[c * 3]; wB = w2[c * 3 + 1]; wC = w2[c * 3 + 2];
      v = (lp == 0) ? (y11 * wB + y12 * wC)
        : (lp == 1) ? (y11 * wA + y12 * wB + y13 * wC)
                    : (y12 * wA + y13 * wB);
      sY2[s] = fmaxf(v + b2[c], 0.f);
    }
  }
  __syncthreads();
  float o0 = b3[l], o1 = b3[l + 64];
  for (int s = 0; s < 96; ++s) {
    float yv = sY2[s];
    o0 += yv * w3t[s * 128 + l];
    o1 += yv * w3t[s * 128 + l + 64];
  }
  float* zrow = z + ((size_t)t * BSZ + b) * ZSTR;
  zrow[1 + l] = o0;
  zrow[1 + l + 64] = o1;
  if (l == 0) {
    int prev = (t > 0) ? alpha[b * TLEN + t - 1] : 0;
    zrow[0] = (float)(a - prev);
  }
  if (l < 3) zrow[129 + l] = 0.f;
}

// K3: persistent LSTM. 128 blocks x 256 threads, 1 block/CU (LDS ~113KB).
// h exchange goes through L3 (coherence point) via agent-scope RELAXED atomics
// (global_load/store sc0 sc1 — bypass non-coherent L1/L2, NO buffer_wbl2/inv).
// Release: h atomic-stores -> s_waitcnt vmcnt(0) -> syncthreads -> relaxed atomic add.
// Acquire: relaxed poll on counter -> h atomic-loads (cannot hit stale cache).
// z / weights stay normal cached loads and persist in L2 across all 256 steps.
__global__ void __launch_bounds__(256, 1) lstm_kernel(
    const float* __restrict__ z, const float* __restrict__ Wc,
    const float* __restrict__ bc, const float* __restrict__ w_hh,
    float* __restrict__ hbuf, int* __restrict__ bar)
{
  __shared__ float sW[64][260];    // w_hh rows (gate*16+jl), padded stride
  __shared__ float sWC[64][132];   // folded input-weight rows
  __shared__ float sH[8][260];     // h slice for this step
  __shared__ float sZ[8][132];     // z rows for next step
  __shared__ float sG[512];        // gate pre-activations exchange
  __shared__ float sBC[64];

  const int tid = threadIdx.x;
  const int btile = (int)blockIdx.x >> 4;   // 0..7
  const int jtile = (int)blockIdx.x & 15;   // 0..15
  const int nl = tid >> 3;                  // 0..31 (row for acc0; +32 for acc1)
  const int bl = tid & 7;                   // local b

  for (int i = tid; i < 64 * 64; i += 256) {          // 64 rows x 64 float4
    int r = i >> 6, c4 = (i & 63) << 2;
    int ng = ((r >> 4) << 8) + (jtile << 4) + (r & 15);
    *(float4*)&sW[r][c4] = *(const float4*)&w_hh[ng * 256 + c4];
  }
  for (int i = tid; i < 64 * 33; i += 256) {          // 64 rows x 33 float4
    int r = i / 33, c4 = (i - r * 33) << 2;
    int ng = ((r >> 4) << 8) + (jtile << 4) + (r & 15);
    *(float4*)&sWC[r][c4] = *(const float4*)&Wc[ng * ZSTR + c4];
  }
  if (tid < 64) {
    int ng = ((tid >> 4) << 8) + (jtile << 4) + (tid & 15);
    sBC[tid] = bc[ng];
  }
  __syncthreads();

  // stage z(t=0) and compute xw for t=0
  for (int i = tid; i < 8 * 33; i += 256) {
    int r = i / 33, c4 = (i - r * 33) << 2;
    *(float4*)&sZ[r][c4] = *(const float4*)&z[(size_t)((btile << 3) + r) * ZSTR + c4];
  }
  __syncthreads();
  float xw0 = sBC[nl], xw1 = sBC[nl + 32];
  #pragma unroll
  for (int k = 0; k < ZSTR; k += 4) {
    float4 zv = *(const float4*)&sZ[bl][k];
    float4 wa = *(const float4*)&sWC[nl][k];
    float4 wb = *(const float4*)&sWC[nl + 32][k];
    xw0 += zv.x * wa.x + zv.y * wa.y + zv.z * wa.z + zv.w * wa.w;
    xw1 += zv.x * wb.x + zv.y * wb.y + zv.z * wb.z + zv.w * wb.w;
  }

  float c_reg = 0.f;
  for (int t = 0; t < TLEN; ++t) {
    if (t > 0) {
      if (tid == 0) {
        const int target = t * LSTM_G;
        while (__hip_atomic_load(bar, __ATOMIC_RELAXED, __HIP_MEMORY_SCOPE_AGENT) < target)
          __builtin_amdgcn_s_sleep(2);
      }
      __syncthreads();
    }
    // stage h(t) — agent-scope relaxed atomic loads (L3-served, bypass L1/L2)
    const float* hsrc = hbuf + ((t & 1) << 14);
    for (int i = tid; i < 2048; i += 256) {
      int r = i >> 8, c = i & 255;
      sH[r][c] = __hip_atomic_load(&hsrc[(((btile << 3) + r) << 8) + c],
                                   __ATOMIC_RELAXED, __HIP_MEMORY_SCOPE_AGENT);
    }
    __syncthreads();

    float a0 = xw0, a1 = xw1;
    #pragma unroll 8
    for (int k = 0; k < 256; k += 4) {
      float4 hv = *(const float4*)&sH[bl][k];
      float4 wa = *(const float4*)&sW[nl][k];
      float4 wb = *(const float4*)&sW[nl + 32][k];
      a0 += hv.x * wa.x + hv.y * wa.y + hv.z * wa.z + hv.w * wa.w;
      a1 += hv.x * wb.x + hv.y * wb.y + hv.z * wb.z + hv.w * wb.w;
    }
    sG[(nl << 3) + bl] = a0;
    sG[((nl + 32) << 3) + bl] = a1;
    __syncthreads();

    if (tid < 128) {
      const int jl = tid >> 3, bb = tid & 7;
      float gi = sG[(jl << 3) + bb];
      float gf = sG[((16 + jl) << 3) + bb];
      float gg = sG[((32 + jl) << 3) + bb];
      float go = sG[((48 + jl) << 3) + bb];
      c_reg = sigm(gf) * c_reg + sigm(gi) * tanh_f(gg);
      float hv = sigm(go) * tanh_f(c_reg);
      float* hdst = hbuf + (((t + 1) & 1) << 14);
      __hip_atomic_store(&hdst[(((btile << 3) + bb) << 8) + (jtile << 4) + jl], hv,
                         __ATOMIC_RELAXED, __HIP_MEMORY_SCOPE_AGENT);
    }
    // release: h stores are write-through to L3; wait until they are there,
    // then publish the arrival. No L2 writeback/invalidate anywhere.
    asm volatile("s_waitcnt vmcnt(0)" ::: "memory");
    __syncthreads();
    if (tid == 0)
      __hip_atomic_fetch_add(bar, 1, __ATOMIC_RELAXED, __HIP_MEMORY_SCOPE_AGENT);

    if (t + 1 < TLEN) {
      // prefetch z(t+1) + xw(t+1): independent of h, overlaps other blocks' waiting
      for (int i = tid; i < 8 * 33; i += 256) {
        int r = i / 33, c4 = (i - r * 33) << 2;
        *(float4*)&sZ[r][c4] =
            *(const float4*)&z[((size_t)(t + 1) * BSZ + (btile << 3) + r) * ZSTR + c4];
      }
      __syncthreads();
      xw0 = sBC[nl]; xw1 = sBC[nl + 32];
      #pragma unroll
      for (int k = 0; k < ZSTR; k += 4) {
        float4 zv = *(const float4*)&sZ[bl][k];
        float4 wa = *(const float4*)&sWC[nl][k];
        float4 wb = *(const float4*)&sWC[nl + 32][k];
        xw0 += zv.x * wa.x + zv.y * wa.y + zv.z * wa.z + zv.w * wa.w;
        xw1 += zv.x * wb.x + zv.y * wb.y + zv.z * wb.z + zv.w * wb.w;
      }
    }
  }
}

// K4: head: out[b] = sigmoid(relu(h@out1_w.T + out1_b) @ out2_w.T + out2_b)
__global__ __launch_bounds__(256) void head_kernel(
    const float* __restrict__ hbuf, const float* __restrict__ o1w,
    const float* __restrict__ o1b, const float* __restrict__ o2w,
    const float* __restrict__ o2b, float* __restrict__ out)
{
  __shared__ float sR[32];
  const int b = blockIdx.x;
  const int tid = threadIdx.x;
  const int m = tid >> 3, g = tid & 7;
  const float* h = hbuf + b * 256;      // final h lives in hbuf[0]
  float acc = 0.f;
  for (int k = g * 32; k < g * 32 + 32; ++k) acc += h[k] * o1w[m * 256 + k];
  acc += __shfl_xor(acc, 1); acc += __shfl_xor(acc, 2); acc += __shfl_xor(acc, 4);
  if (g == 0) sR[m] = fmaxf(acc + o1b[m], 0.f);
  __syncthreads();
  if (tid == 0) {
    float s = o2b[0];
    for (int mm = 0; mm < 32; ++mm) s += sR[mm] * o2w[mm];
    out[b] = sigm(s);
  }
}

extern "C" void kernel_launch(void* const* d_in, const int* in_sizes, int n_in,
                              void* d_out, int out_size, void* d_ws, size_t ws_size,
                              hipStream_t stream) {
  (void)in_sizes; (void)n_in; (void)out_size; (void)ws_size;
  const int*   alpha = (const int*)  d_in[0];
  const float* sound = (const float*)d_in[1];
  const float* w1    = (const float*)d_in[2];
  const float* b1    = (const float*)d_in[3];
  const float* w2    = (const float*)d_in[4];
  const float* b2    = (const float*)d_in[5];
  const float* w3    = (const float*)d_in[6];
  const float* b3    = (const float*)d_in[7];
  const float* linw  = (const float*)d_in[8];
  const float* linb  = (const float*)d_in[9];
  const float* wih   = (const float*)d_in[10];
  const float* whh   = (const float*)d_in[11];
  const float* bih   = (const float*)d_in[12];
  const float* bhh   = (const float*)d_in[13];
  const float* o1w   = (const float*)d_in[14];
  const float* o1b   = (const float*)d_in[15];
  const float* o2w   = (const float*)d_in[16];
  const float* o2b   = (const float*)d_in[17];

  float* z    = (float*)d_ws;            // T*B*132           = 2,162,688 f
  float* Wc   = z + 2162688;             // 1024*132          =   135,168 f
  float* bc   = Wc + 135168;             // 1024 f
  float* w3t  = bc + 1024;               // 96*128            =    12,288 f
  float* hbuf = w3t + 12288;             // 2*64*256          =    32,768 f
  int*   bar  = (int*)(hbuf + 32768);    // counter

  hipMemsetAsync(hbuf, 0, 32768 * 4 + 256, stream);   // h0 = 0, barrier = 0

  prep_kernel<<<1024, 256, 0, stream>>>(wih, linw, linb, bih, bhh, Wc, bc);
  transpose_w3<<<48, 256, 0, stream>>>(w3, w3t);
  conv_kernel<<<BSZ * TLEN, 64, 0, stream>>>(alpha, sound, w1, b1, w2, b2, w3t, b3, z);
  lstm_kernel<<<LSTM_G, 256, 0, stream>>>(z, Wc, bc, whh, hbuf, bar);
  head_kernel<<<BSZ, 256, 0, stream>>>(hbuf, o1w, o1b, o2w, o2b, (float*)d_out);
}

// Round 3
// 1104.786 us; speedup vs baseline: 4.5067x; 1.8978x over previous
//
#include <hip/hip_runtime.h>
#include <math.h>

#define BSZ 64
#define TLEN 256
#define LSND 65536
#define ZSLOTS 144        // z padded: 4 k-slices x 36 (33 real + 3 zero-pad)

__device__ __forceinline__ float sigm(float x) { return 1.f / (1.f + __expf(-x)); }
__device__ __forceinline__ float tanh_f(float x) {
  float e = __expf(-2.f * fabsf(x));
  return copysignf((1.f - e) / (1.f + e), x);
}
__device__ __forceinline__ int zslot(int k) { return (k / 33) * 36 + (k % 33); }

// K1: fold linear into w_ih:  Wc[n][j] = sum_k w_ih[n,k]*lin_w[k,j]  (1024 x 132, pads zero)
//     bc[n] = w_ih[n,:]@lin_b + b_ih[n] + b_hh[n]
__global__ __launch_bounds__(256) void prep_kernel(
    const float* __restrict__ w_ih, const float* __restrict__ lin_w,
    const float* __restrict__ lin_b, const float* __restrict__ b_ih,
    const float* __restrict__ b_hh, float* __restrict__ Wc, float* __restrict__ bc)
{
  __shared__ float sRow[256];
  const int n = blockIdx.x;
  const int j = threadIdx.x;
  sRow[j] = w_ih[n * 256 + j];
  __syncthreads();
  if (j < 132) {
    float acc = 0.f;
    if (j < 129) {
      for (int k = 0; k < 256; ++k) acc += sRow[k] * lin_w[k * 129 + j];
    }
    Wc[n * 132 + j] = acc;
  } else if (j == 255) {
    float acc = b_ih[n] + b_hh[n];
    for (int k = 0; k < 256; ++k) acc += sRow[k] * lin_b[k];
    bc[n] = acc;
  }
}

// K1b: w3t[s][o] = conv3_w[o][s]
__global__ __launch_bounds__(256) void transpose_w3(const float* __restrict__ w3,
                                                    float* __restrict__ w3t)
{
  int i = blockIdx.x * 256 + threadIdx.x;
  if (i < 96 * 128) { int s = i >> 7, o = i & 127; w3t[i] = w3[o * 96 + s]; }
}

// K2: gather + conv1/conv2/conv3 -> z[t][b][ZSLOTS] in the ks-padded slot layout.
__global__ __launch_bounds__(64) void conv_kernel(
    const int* __restrict__ alpha, const float* __restrict__ sound,
    const float* __restrict__ w1, const float* __restrict__ b1v,
    const float* __restrict__ w2, const float* __restrict__ b2,
    const float* __restrict__ w3t, const float* __restrict__ b3,
    float* __restrict__ z)
{
  __shared__ float win[2048];
  __shared__ float sY2[96];
  const int l = threadIdx.x;
  const int b = blockIdx.x >> 8;
  const int t = blockIdx.x & 255;
  const int a = alpha[b * TLEN + t];
  const int a0 = a - 1024;
  const float* srow = sound + (size_t)b * LSND;
  for (int x = l; x < 2048; x += 64) {
    int p = a0 + x;
    win[x] = (p >= 0 && p < LSND) ? srow[p] : 0.f;
  }
  __syncthreads();
  float acc0 = 0.f, acc1 = 0.f, acc2 = 0.f;
  for (int f = l; f < 2046; f += 64) {
    float wv = w1[f];
    acc0 += win[f] * wv;
    acc1 += win[f + 1] * wv;
    acc2 += win[f + 2] * wv;
  }
  for (int m = 32; m; m >>= 1) {
    acc0 += __shfl_xor(acc0, m);
    acc1 += __shfl_xor(acc1, m);
    acc2 += __shfl_xor(acc2, m);
  }
  const float bb = b1v[0];
  const float y11 = acc0 + bb, y12 = acc1 + bb, y13 = acc2 + bb;
  {
    int s = l;
    int c = s / 3, lp = s - c * 3;
    float wA = w2[c * 3], wB = w2[c * 3 + 1], wC = w2[c * 3 + 2];
    float v = (lp == 0) ? (y11 * wB + y12 * wC)
            : (lp == 1) ? (y11 * wA + y12 * wB + y13 * wC)
                        : (y12 * wA + y13 * wB);
    sY2[s] = fmaxf(v + b2[c], 0.f);
    if (l < 32) {
      s = 64 + l; c = s / 3; lp = s - c * 3;
      wA = w2[c * 3]; wB = w2[c * 3 + 1]; wC = w2[c * 3 + 2];
      v = (lp == 0) ? (y11 * wB + y12 * wC)
        : (lp == 1) ? (y11 * wA + y12 * wB + y13 * wC)
                    : (y12 * wA + y13 * wB);
      sY2[s] = fmaxf(v + b2[c], 0.f);
    }
  }
  __syncthreads();
  float o0 = b3[l], o1 = b3[l + 64];
  for (int s = 0; s < 96; ++s) {
    float yv = sY2[s];
    o0 += yv * w3t[s * 128 + l];
    o1 += yv * w3t[s * 128 + l + 64];
  }
  float* zrow = z + ((size_t)t * BSZ + b) * ZSLOTS;
  zrow[zslot(1 + l)] = o0;
  zrow[zslot(65 + l)] = o1;
  if (l == 0) {
    int prev = (t > 0) ? alpha[b * TLEN + t - 1] : 0;
    zrow[0] = (float)(a - prev);
  }
  if (l < 15) {  // zero the 15 unused pad slots
    int s = (l < 9) ? ((l / 3) * 36 + 33 + (l % 3)) : (138 + (l - 9));
    zrow[s] = 0.f;
  }
}

// K3: persistent LSTM, 256 blocks x 256 threads (16 btiles x 16 jtiles), no barriers
// between blocks: h exchanged via tagged u64 mailboxes (f32 payload | step tag) with
// agent-scope relaxed atomics (L3-served, bypass stale L1/L2). w_hh and Wc rows live
// in VGPRs (each thread: 1 row x K-slice); h/z read as wave-uniform LDS broadcasts.
// Per step: wave-local poll -> dot (K = 256 h + 132 z folded) -> cross-wave reduce
// -> gates -> tagged store. Two __syncthreads per step.
__global__ void __launch_bounds__(256, 1) lstm_kernel(
    const float* __restrict__ z, const float* __restrict__ Wc,
    const float* __restrict__ bc, const float* __restrict__ w_hh,
    unsigned long long* __restrict__ hbuf, float* __restrict__ hfin)
{
  __shared__ float sH[4][408];   // [local b][0..255 = h | 256..399 = z slots]
  __shared__ float sP[64][20];   // partials [row][b*4+ks]
  __shared__ float sG[256];      // gate preacts [row*4+b]
  __shared__ float sBC[64];

  const int tid = threadIdx.x;
  const int btile = (int)blockIdx.x >> 4;   // 0..15 -> b in [btile*4, +4)
  const int jt    = (int)blockIdx.x & 15;   // h-cols [jt*16, +16)
  const int w  = tid >> 6;                  // wave = K-slice index (0..3)
  const int nl = tid & 63;                  // local gate row (0..63)
  const int ng = ((nl >> 4) << 8) + (jt << 4) + (nl & 15);  // global gate row

  // ---- one-time: weights into registers ----
  float4 wh[16];
  #pragma unroll
  for (int i = 0; i < 16; ++i)
    wh[i] = *(const float4*)&w_hh[ng * 256 + (w << 6) + (i << 2)];
  float4 wz[9];
  #pragma unroll
  for (int i = 0; i < 9; ++i) {
    float c0 = (i * 4 + 0 < 33) ? Wc[ng * 132 + w * 33 + i * 4 + 0] : 0.f;
    float c1 = (i * 4 + 1 < 33) ? Wc[ng * 132 + w * 33 + i * 4 + 1] : 0.f;
    float c2 = (i * 4 + 2 < 33) ? Wc[ng * 132 + w * 33 + i * 4 + 2] : 0.f;
    float c3 = (i * 4 + 3 < 33) ? Wc[ng * 132 + w * 33 + i * 4 + 3] : 0.f;
    wz[i] = make_float4(c0, c1, c2, c3);
  }
  if (tid < 64) sBC[tid] = bc[((tid >> 4) << 8) + (jt << 4) + (tid & 15)];

  // ---- z staging: sH z-region for t=0; zpre register for t=1 ----
  const int zb = (tid < 144) ? tid / 36 : 0;
  const int zc4 = (tid < 144) ? (tid - zb * 36) << 2 : 0;
  float4 zpre = make_float4(0.f, 0.f, 0.f, 0.f);
  if (tid < 144) {
    *(float4*)&sH[zb][256 + zc4] =
        *(const float4*)&z[((size_t)0 * BSZ + (btile << 2) + zb) * ZSLOTS + zc4];
    zpre = *(const float4*)&z[((size_t)1 * BSZ + (btile << 2) + zb) * ZSLOTS + zc4];
  }
  float c_reg = 0.f;
  __syncthreads();

  // poll role: lane ll = tid&63: b = ll&3, jp = ll>>2; words j = w*64 + jp + s*16
  const int pb = tid & 3;
  const int pjp = (tid & 63) >> 2;
  const int pbase = ((((btile << 2) + pb) << 8) | (w << 6) | pjp);

  for (int t = 0; t < TLEN; ++t) {
    // ---- wave-local poll + stage h (no barrier: wave consumes what it wrote) ----
    {
      const unsigned long long* hsrc = hbuf + ((size_t)(t & 1) << 14);
      const unsigned tagw = (unsigned)t;
      int rem = 15;
      while (rem) {
        #pragma unroll
        for (int s = 0; s < 4; ++s) {
          if (rem & (1 << s)) {
            unsigned long long v = __hip_atomic_load(hsrc + pbase + (s << 4),
                __ATOMIC_RELAXED, __HIP_MEMORY_SCOPE_AGENT);
            if ((unsigned)v == tagw) {
              sH[pb][(w << 6) | (pjp + (s << 4))] = __uint_as_float((unsigned)(v >> 32));
              rem &= ~(1 << s);
            }
          }
        }
      }
    }
    // ---- dot: thread = (row nl, K-slice w), 4 local b via LDS broadcast ----
    float a0 = 0.f, a1 = 0.f, a2 = 0.f, a3 = 0.f;
    const int hb = w << 6;
    #pragma unroll
    for (int i = 0; i < 16; ++i) {
      const float4 wv = wh[i];
      float4 h;
      h = *(const float4*)&sH[0][hb + (i << 2)]; a0 += wv.x*h.x + wv.y*h.y + wv.z*h.z + wv.w*h.w;
      h = *(const float4*)&sH[1][hb + (i << 2)]; a1 += wv.x*h.x + wv.y*h.y + wv.z*h.z + wv.w*h.w;
      h = *(const float4*)&sH[2][hb + (i << 2)]; a2 += wv.x*h.x + wv.y*h.y + wv.z*h.z + wv.w*h.w;
      h = *(const float4*)&sH[3][hb + (i << 2)]; a3 += wv.x*h.x + wv.y*h.y + wv.z*h.z + wv.w*h.w;
    }
    const int zbase = 256 + w * 36;
    #pragma unroll
    for (int i = 0; i < 9; ++i) {
      const float4 wv = wz[i];
      float4 v;
      v = *(const float4*)&sH[0][zbase + (i << 2)]; a0 += wv.x*v.x + wv.y*v.y + wv.z*v.z + wv.w*v.w;
      v = *(const float4*)&sH[1][zbase + (i << 2)]; a1 += wv.x*v.x + wv.y*v.y + wv.z*v.z + wv.w*v.w;
      v = *(const float4*)&sH[2][zbase + (i << 2)]; a2 += wv.x*v.x + wv.y*v.y + wv.z*v.z + wv.w*v.w;
      v = *(const float4*)&sH[3][zbase + (i << 2)]; a3 += wv.x*v.x + wv.y*v.y + wv.z*v.z + wv.w*v.w;
    }
    sP[nl][0 + w] = a0;
    sP[nl][4 + w] = a1;
    sP[nl][8 + w] = a2;
    sP[nl][12 + w] = a3;
    __syncthreads();                       // B2: partials complete
    {
      const int rn = tid >> 2, rb = tid & 3;
      const float4 p = *(const float4*)&sP[rn][rb << 2];
      sG[tid] = p.x + p.y + p.z + p.w + sBC[rn];
    }
    if (t + 1 < TLEN && tid < 144)         // stage z(t+1) (read next dot, after B3)
      *(float4*)&sH[zb][256 + zc4] = zpre;
    __syncthreads();                       // B3: sG + z-region ready
    if (tid < 64) {
      float gi = sG[tid];
      float gf = sG[64 + tid];
      float gg = sG[128 + tid];
      float go = sG[192 + tid];
      c_reg = sigm(gf) * c_reg + sigm(gi) * tanh_f(gg);
      float hv = sigm(go) * tanh_f(c_reg);
      const int jl = tid >> 2, bb = tid & 3;
      const int widx = ((((btile << 2) + bb) << 8) | ((jt << 4) + jl));
      unsigned long long pk =
          ((unsigned long long)__float_as_uint(hv) << 32) | (unsigned)(t + 1);
      __hip_atomic_store(hbuf + (((size_t)((t + 1) & 1)) << 14) + widx, pk,
                         __ATOMIC_RELAXED, __HIP_MEMORY_SCOPE_AGENT);
      if (t == TLEN - 1) hfin[widx] = hv;
    }
    if (t + 2 < TLEN && tid < 144)         // prefetch z(t+2) into registers
      zpre = *(const float4*)&z[((size_t)(t + 2) * BSZ + (btile << 2) + zb) * ZSLOTS + zc4];
  }
}

// K4: head: out[b] = sigmoid(relu(h@out1_w.T + out1_b) @ out2_w.T + out2_b)
__global__ __launch_bounds__(256) void head_kernel(
    const float* __restrict__ hfin, const float* __restrict__ o1w,
    const float* __restrict__ o1b, const float* __restrict__ o2w,
    const float* __restrict__ o2b, float* __restrict__ out)
{
  __shared__ float sR[32];
  const int b = blockIdx.x;
  const int tid = threadIdx.x;
  const int m = tid >> 3, g = tid & 7;
  const float* h = hfin + b * 256;
  float acc = 0.f;
  for (int k = g * 32; k < g * 32 + 32; ++k) acc += h[k] * o1w[m * 256 + k];
  acc += __shfl_xor(acc, 1); acc += __shfl_xor(acc, 2); acc += __shfl_xor(acc, 4);
  if (g == 0) sR[m] = fmaxf(acc + o1b[m], 0.f);
  __syncthreads();
  if (tid == 0) {
    float s = o2b[0];
    for (int mm = 0; mm < 32; ++mm) s += sR[mm] * o2w[mm];
    out[b] = sigm(s);
  }
}

extern "C" void kernel_launch(void* const* d_in, const int* in_sizes, int n_in,
                              void* d_out, int out_size, void* d_ws, size_t ws_size,
                              hipStream_t stream) {
  (void)in_sizes; (void)n_in; (void)out_size; (void)ws_size;
  const int*   alpha = (const int*)  d_in[0];
  const float* sound = (const float*)d_in[1];
  const float* w1    = (const float*)d_in[2];
  const float* b1    = (const float*)d_in[3];
  const float* w2    = (const float*)d_in[4];
  const float* b2    = (const float*)d_in[5];
  const float* w3    = (const float*)d_in[6];
  const float* b3    = (const float*)d_in[7];
  const float* linw  = (const float*)d_in[8];
  const float* linb  = (const float*)d_in[9];
  const float* wih   = (const float*)d_in[10];
  const float* whh   = (const float*)d_in[11];
  const float* bih   = (const float*)d_in[12];
  const float* bhh   = (const float*)d_in[13];
  const float* o1w   = (const float*)d_in[14];
  const float* o1b   = (const float*)d_in[15];
  const float* o2w   = (const float*)d_in[16];
  const float* o2b   = (const float*)d_in[17];

  float* z    = (float*)d_ws;                 // 256*64*144 = 2,359,296 f
  float* Wc   = z + 2359296;                  // 1024*132   =   135,168 f
  float* bc   = Wc + 135168;                  // 1024 f
  float* w3t  = bc + 1024;                    // 12,288 f
  float* hfin = w3t + 12288;                  // 16,384 f
  unsigned long long* hbuf =
      (unsigned long long*)(hfin + 16384);    // 2*64*256 u64 = 256 KiB (8B-aligned)

  hipMemsetAsync(hbuf, 0, 32768 * 8, stream); // tag 0 / h0 = 0

  prep_kernel<<<1024, 256, 0, stream>>>(wih, linw, linb, bih, bhh, Wc, bc);
  transpose_w3<<<48, 256, 0, stream>>>(w3, w3t);
  conv_kernel<<<BSZ * TLEN, 64, 0, stream>>>(alpha, sound, w1, b1, w2, b2, w3t, b3, z);
  lstm_kernel<<<256, 256, 0, stream>>>(z, Wc, bc, whh, hbuf, hfin);
  head_kernel<<<BSZ, 256, 0, stream>>>(hfin, o1w, o1b, o2w, o2b, (float*)d_out);
}